// Round 16
// baseline (291.091 us; speedup 1.0000x reference)
//
#include <hip/hip_runtime.h>
#include <hip/hip_bf16.h>
#include <math.h>

#define N_NODES 32768
#define E_EDGES 1048576
#define CIN 128
#define CHID 256
#define COUT 128

typedef __attribute__((ext_vector_type(8))) short bf16x8;
typedef __attribute__((ext_vector_type(4))) float f32x4;

// bf16 <-> f32 helpers. Gather tables + GEMM operands stored bf16.
__device__ inline float bf2f(unsigned short u) {
    union { unsigned int i; float f; } c;
    c.i = ((unsigned int)u) << 16;
    return c.f;
}
__device__ inline unsigned short f2bf(float f) {
    __hip_bfloat16 h = __float2bfloat16(f);  // RNE
    return *reinterpret_cast<unsigned short*>(&h);
}

// ---------------------------------------------------------------------------
// CSR build: deg+rank count -> exclusive scan (+dinv) -> atomic-free fill
// ---------------------------------------------------------------------------
__global__ __launch_bounds__(256) void deg_kernel(const int* __restrict__ dst,
                                                  int* __restrict__ deg,
                                                  int* __restrict__ rank) {
    int idx = blockIdx.x * blockDim.x + threadIdx.x;  // int2 index
    int2 d2 = ((const int2*)dst)[idx];
    int r0 = atomicAdd(&deg[d2.x], 1);
    int r1 = atomicAdd(&deg[d2.y], 1);
    int2 r2; r2.x = r0; r2.y = r1;
    ((int2*)rank)[idx] = r2;
}

__global__ __launch_bounds__(1024) void scan_kernel(const int* __restrict__ deg,
                                                    int* __restrict__ offs,
                                                    float* __restrict__ dinv) {
    __shared__ int s[1024];
    int t = threadIdx.x;
    int base = t * 32;
    int ts = 0;
#pragma unroll
    for (int j = 0; j < 32; ++j) ts += deg[base + j];
    s[t] = ts;
    __syncthreads();
    for (int off = 1; off < 1024; off <<= 1) {
        int v = (t >= off) ? s[t - off] : 0;
        __syncthreads();
        s[t] += v;
        __syncthreads();
    }
    int run = s[t] - ts;
    for (int j = 0; j < 32; ++j) {
        int idx = base + j;
        int d = deg[idx];
        offs[idx] = run;
        dinv[idx] = 1.0f / sqrtf((float)(d + 1));  // deg includes self-loop
        run += d;
    }
    if (t == 1023) offs[N_NODES] = s[1023];
}

__global__ __launch_bounds__(256) void fill_kernel(const int* __restrict__ src,
                                                   const int* __restrict__ dst,
                                                   const int* __restrict__ rank,
                                                   const int* __restrict__ offs,
                                                   int* __restrict__ csr) {
    int idx = blockIdx.x * blockDim.x + threadIdx.x;  // int4 index
    int4 d4 = ((const int4*)dst)[idx];
    int4 s4 = ((const int4*)src)[idx];
    int4 r4 = ((const int4*)rank)[idx];
    csr[offs[d4.x] + r4.x] = s4.x;
    csr[offs[d4.y] + r4.y] = s4.y;
    csr[offs[d4.z] + r4.z] = s4.z;
    csr[offs[d4.w] + r4.w] = s4.w;
}

// ---------------------------------------------------------------------------
// QUANTX: xq[i][c] = bf16( x[i][c] * dinv[i] )
// ---------------------------------------------------------------------------
__global__ __launch_bounds__(256) void quantx_kernel(const float* __restrict__ x,
                                                     const float* __restrict__ dinv,
                                                     unsigned short* __restrict__ xq) {
    int idx = blockIdx.x * 256 + threadIdx.x;
    int row = idx >> 5;
    float dv = dinv[row];
    float4 v = ((const float4*)x)[idx];
    ushort4 o;
    o.x = f2bf(v.x * dv); o.y = f2bf(v.y * dv);
    o.z = f2bf(v.z * dv); o.w = f2bf(v.w * dv);
    ((ushort4*)xq)[idx] = o;
}

// ---------------------------------------------------------------------------
// QUANTW: pre-transpose + bf16-quantize weights for contiguous MFMA B-frags.
// ---------------------------------------------------------------------------
__global__ __launch_bounds__(256) void quantw_kernel(const float* __restrict__ W1,
                                                     const float* __restrict__ W2,
                                                     unsigned short* __restrict__ w1t,
                                                     unsigned short* __restrict__ w2t) {
    int idx = blockIdx.x * 256 + threadIdx.x;  // 0..65535
    if (idx < CHID * CIN) {
        int c = idx >> 7, k = idx & 127;       // W1T[c][k] = W1[k][c]
        w1t[idx] = f2bf(W1[k * CHID + c]);
    } else {
        int j = idx - CHID * CIN;
        int o = j >> 8, k = j & 255;           // W2T[o][k] = W2[k][o]
        w2t[j] = f2bf(W2[k * COUT + o]);
    }
}

// ---------------------------------------------------------------------------
// AGGX: uq[i] = bf16( dinv[i]*(sum_{e:dst=i} xq[src] + xq[i]) )
// R15 evidence: all kernels <44us; aggs are the biggest pair (~60us each).
// Half-wave gathers: lanes 0-31 take even edges, 32-63 odd edges; each
// 256B row is fetched by 32 lanes x ushort4 -> TWO rows per instruction,
// 16 rows in flight with the 8-deep pipeline. shfl_xor(32) merges halves.
// ---------------------------------------------------------------------------
__global__ __launch_bounds__(256) void aggx_kernel(const unsigned short* __restrict__ xq,
                                                   const int* __restrict__ offs,
                                                   const int* __restrict__ csr,
                                                   const float* __restrict__ dinv,
                                                   unsigned short* __restrict__ uq) {
    int tid = threadIdx.x, wave = tid >> 6, lane = tid & 63;
    int half = lane >> 5, sl = lane & 31;
    int c0 = sl * 4;  // 4 bf16 channels per lane (8B), 32 lanes = 256B row

    for (int g = blockIdx.x; g < N_NODES / 4; g += gridDim.x) {
        int node = g * 4 + wave;
        int s0 = offs[node];
        int n = offs[node + 1] - s0;

        float4 acc = make_float4(0.f, 0.f, 0.f, 0.f);
        if (half == 0) {  // self loop counted once
            ushort4 sv = *(const ushort4*)(&xq[(size_t)node * CIN + c0]);
            acc.x = bf2f(sv.x); acc.y = bf2f(sv.y);
            acc.z = bf2f(sv.z); acc.w = bf2f(sv.w);
        }

        int nh = (n - half + 1) >> 1;  // my half's edge count (stride-2 list)
        int base = s0 + half;
        int nb = nh >> 3;
        int k = 0;
        int i0 = 0, i1 = 0, i2 = 0, i3 = 0, i4 = 0, i5 = 0, i6 = 0, i7 = 0;
        if (nb > 0) {
            i0 = csr[base + 0];  i1 = csr[base + 2];  i2 = csr[base + 4];  i3 = csr[base + 6];
            i4 = csr[base + 8];  i5 = csr[base + 10]; i6 = csr[base + 12]; i7 = csr[base + 14];
        }
        for (int t = 0; t < nb; ++t) {
            ushort4 v0 = *(const ushort4*)(&xq[(size_t)i0 * CIN + c0]);
            ushort4 v1 = *(const ushort4*)(&xq[(size_t)i1 * CIN + c0]);
            ushort4 v2 = *(const ushort4*)(&xq[(size_t)i2 * CIN + c0]);
            ushort4 v3 = *(const ushort4*)(&xq[(size_t)i3 * CIN + c0]);
            ushort4 v4 = *(const ushort4*)(&xq[(size_t)i4 * CIN + c0]);
            ushort4 v5 = *(const ushort4*)(&xq[(size_t)i5 * CIN + c0]);
            ushort4 v6 = *(const ushort4*)(&xq[(size_t)i6 * CIN + c0]);
            ushort4 v7 = *(const ushort4*)(&xq[(size_t)i7 * CIN + c0]);
            int nk = k + 8;
            int j0 = 0, j1 = 0, j2 = 0, j3 = 0, j4 = 0, j5 = 0, j6 = 0, j7 = 0;
            if (t + 1 < nb) {
                const int* cp = csr + base + 2 * nk;
                j0 = cp[0];  j1 = cp[2];  j2 = cp[4];  j3 = cp[6];
                j4 = cp[8];  j5 = cp[10]; j6 = cp[12]; j7 = cp[14];
            }
            acc.x += ((bf2f(v0.x) + bf2f(v1.x)) + (bf2f(v2.x) + bf2f(v3.x))) +
                     ((bf2f(v4.x) + bf2f(v5.x)) + (bf2f(v6.x) + bf2f(v7.x)));
            acc.y += ((bf2f(v0.y) + bf2f(v1.y)) + (bf2f(v2.y) + bf2f(v3.y))) +
                     ((bf2f(v4.y) + bf2f(v5.y)) + (bf2f(v6.y) + bf2f(v7.y)));
            acc.z += ((bf2f(v0.z) + bf2f(v1.z)) + (bf2f(v2.z) + bf2f(v3.z))) +
                     ((bf2f(v4.z) + bf2f(v5.z)) + (bf2f(v6.z) + bf2f(v7.z)));
            acc.w += ((bf2f(v0.w) + bf2f(v1.w)) + (bf2f(v2.w) + bf2f(v3.w))) +
                     ((bf2f(v4.w) + bf2f(v5.w)) + (bf2f(v6.w) + bf2f(v7.w)));
            k = nk;
            i0 = j0; i1 = j1; i2 = j2; i3 = j3; i4 = j4; i5 = j5; i6 = j6; i7 = j7;
        }
        for (; k + 4 <= nh; k += 4) {
            const int* cp = csr + base + 2 * k;
            int k0 = cp[0], k1 = cp[2], k2 = cp[4], k3 = cp[6];
            ushort4 v0 = *(const ushort4*)(&xq[(size_t)k0 * CIN + c0]);
            ushort4 v1 = *(const ushort4*)(&xq[(size_t)k1 * CIN + c0]);
            ushort4 v2 = *(const ushort4*)(&xq[(size_t)k2 * CIN + c0]);
            ushort4 v3 = *(const ushort4*)(&xq[(size_t)k3 * CIN + c0]);
            acc.x += (bf2f(v0.x) + bf2f(v1.x)) + (bf2f(v2.x) + bf2f(v3.x));
            acc.y += (bf2f(v0.y) + bf2f(v1.y)) + (bf2f(v2.y) + bf2f(v3.y));
            acc.z += (bf2f(v0.z) + bf2f(v1.z)) + (bf2f(v2.z) + bf2f(v3.z));
            acc.w += (bf2f(v0.w) + bf2f(v1.w)) + (bf2f(v2.w) + bf2f(v3.w));
        }
        for (; k < nh; ++k) {
            int s = csr[base + 2 * k];
            ushort4 v = *(const ushort4*)(&xq[(size_t)s * CIN + c0]);
            acc.x += bf2f(v.x); acc.y += bf2f(v.y);
            acc.z += bf2f(v.z); acc.w += bf2f(v.w);
        }
        // merge odd-edge half into even-edge half
        acc.x += __shfl_xor(acc.x, 32);
        acc.y += __shfl_xor(acc.y, 32);
        acc.z += __shfl_xor(acc.z, 32);
        acc.w += __shfl_xor(acc.w, 32);
        if (half == 0) {
            float dv = dinv[node];
            ushort4 o;
            o.x = f2bf(acc.x * dv); o.y = f2bf(acc.y * dv);
            o.z = f2bf(acc.z * dv); o.w = f2bf(acc.w * dv);
            *(ushort4*)(&uq[(size_t)node * CIN + c0]) = o;
        }
    }
}

// ---------------------------------------------------------------------------
// GEMM1 (MFMA): h1[m][c] = (uq @ W1)[m][c] + b1[c], fused BN stats.
// ---------------------------------------------------------------------------
__global__ __launch_bounds__(256) void gemm1_kernel(const unsigned short* __restrict__ uq,
                                                    const unsigned short* __restrict__ w1t,
                                                    const float* __restrict__ b1,
                                                    float* __restrict__ h1,
                                                    float* __restrict__ stats) {
    int tid = threadIdx.x, wv = tid >> 6, l = tid & 63;
    int rowBase = blockIdx.x * 64 + wv * 16;
    int lm = l & 15, lg = l >> 4;

    const unsigned short* up = uq + (size_t)(rowBase + lm) * CIN + lg * 8;
    bf16x8 afr0 = *(const bf16x8*)(up + 0);
    bf16x8 afr1 = *(const bf16x8*)(up + 32);
    bf16x8 afr2 = *(const bf16x8*)(up + 64);
    bf16x8 afr3 = *(const bf16x8*)(up + 96);

    f32x4 acc[16];
#pragma unroll
    for (int t = 0; t < 16; ++t) acc[t] = (f32x4){0.f, 0.f, 0.f, 0.f};

    const unsigned short* wb = w1t + (size_t)lm * CIN + lg * 8;
#pragma unroll
    for (int t = 0; t < 16; ++t) {
        const unsigned short* wt = wb + (size_t)t * 16 * CIN;
        bf16x8 b0 = *(const bf16x8*)(wt + 0);
        bf16x8 b1f = *(const bf16x8*)(wt + 32);
        bf16x8 b2 = *(const bf16x8*)(wt + 64);
        bf16x8 b3 = *(const bf16x8*)(wt + 96);
        acc[t] = __builtin_amdgcn_mfma_f32_16x16x32_bf16(afr0, b0, acc[t], 0, 0, 0);
        acc[t] = __builtin_amdgcn_mfma_f32_16x16x32_bf16(afr1, b1f, acc[t], 0, 0, 0);
        acc[t] = __builtin_amdgcn_mfma_f32_16x16x32_bf16(afr2, b2, acc[t], 0, 0, 0);
        acc[t] = __builtin_amdgcn_mfma_f32_16x16x32_bf16(afr3, b3, acc[t], 0, 0, 0);
    }

    __shared__ float red[4][CHID];  // 4 KB
    float ps[16], pq[16];
#pragma unroll
    for (int t = 0; t < 16; ++t) {
        float bb = b1[t * 16 + lm];
        float s = 0.f, q = 0.f;
#pragma unroll
        for (int r = 0; r < 4; ++r) {
            float h = acc[t][r] + bb;
            h1[(size_t)(rowBase + lg * 4 + r) * CHID + t * 16 + lm] = h;
            s += h; q += h * h;
        }
        s += __shfl_xor(s, 16); s += __shfl_xor(s, 32);
        q += __shfl_xor(q, 16); q += __shfl_xor(q, 32);
        ps[t] = s; pq[t] = q;
    }
    if (l < 16) {
#pragma unroll
        for (int t = 0; t < 16; ++t) red[wv][t * 16 + l] = ps[t];
    }
    __syncthreads();
    {
        float v = red[0][tid & 255] + red[1][tid & 255] + red[2][tid & 255] + red[3][tid & 255];
        atomicAdd(&stats[tid], v);
    }
    __syncthreads();
    if (l < 16) {
#pragma unroll
        for (int t = 0; t < 16; ++t) red[wv][t * 16 + l] = pq[t];
    }
    __syncthreads();
    {
        float v = red[0][tid & 255] + red[1][tid & 255] + red[2][tid & 255] + red[3][tid & 255];
        atomicAdd(&stats[CHID + tid], v);
    }
}

// ---------------------------------------------------------------------------
// BN prep: per-channel affine a*h+bb equivalent to BN(gamma,beta)
// ---------------------------------------------------------------------------
__global__ __launch_bounds__(256) void bnprep_kernel(const float* __restrict__ stats,
                                                     const float* __restrict__ gamma,
                                                     const float* __restrict__ beta,
                                                     float* __restrict__ ab) {
    int c = threadIdx.x;
    float mean = stats[c] * (1.0f / N_NODES);
    float var = stats[CHID + c] * (1.0f / N_NODES) - mean * mean;
    float a = gamma[c] / sqrtf(var + 1e-5f);
    ab[c] = a;
    ab[CHID + c] = beta[c] - mean * a;
}

// ---------------------------------------------------------------------------
// GEMM2 (MFMA): g2[m][o] = bf16( dinv[m] * (relu(a*h1+bb) @ W2)[m][o] )
// ---------------------------------------------------------------------------
__global__ __launch_bounds__(256) void gemm2_kernel(const float* __restrict__ h1,
                                                    const float* __restrict__ ab,
                                                    const unsigned short* __restrict__ w2t,
                                                    const float* __restrict__ dinv,
                                                    unsigned short* __restrict__ g2) {
    int tid = threadIdx.x, wv = tid >> 6, l = tid & 63;
    int rowBase = blockIdx.x * 64 + wv * 16;
    int lm = l & 15, lg = l >> 4;

    f32x4 acc[8];
#pragma unroll
    for (int t = 0; t < 8; ++t) acc[t] = (f32x4){0.f, 0.f, 0.f, 0.f};

    const float* hp = h1 + (size_t)(rowBase + lm) * CHID + lg * 8;
    const unsigned short* wb = w2t + (size_t)lm * CHID + lg * 8;

#pragma unroll
    for (int s = 0; s < 8; ++s) {
        int k0 = s * 32 + lg * 8;
        float4 h0 = *(const float4*)(hp + s * 32);
        float4 h1v = *(const float4*)(hp + s * 32 + 4);
        float4 a0 = *(const float4*)(&ab[k0]);
        float4 a1 = *(const float4*)(&ab[k0 + 4]);
        float4 c0 = *(const float4*)(&ab[CHID + k0]);
        float4 c1 = *(const float4*)(&ab[CHID + k0 + 4]);
        bf16x8 afr;
        afr[0] = (short)f2bf(fmaxf(h0.x * a0.x + c0.x, 0.f));
        afr[1] = (short)f2bf(fmaxf(h0.y * a0.y + c0.y, 0.f));
        afr[2] = (short)f2bf(fmaxf(h0.z * a0.z + c0.z, 0.f));
        afr[3] = (short)f2bf(fmaxf(h0.w * a0.w + c0.w, 0.f));
        afr[4] = (short)f2bf(fmaxf(h1v.x * a1.x + c1.x, 0.f));
        afr[5] = (short)f2bf(fmaxf(h1v.y * a1.y + c1.y, 0.f));
        afr[6] = (short)f2bf(fmaxf(h1v.z * a1.z + c1.z, 0.f));
        afr[7] = (short)f2bf(fmaxf(h1v.w * a1.w + c1.w, 0.f));
#pragma unroll
        for (int t = 0; t < 8; ++t) {
            bf16x8 bfr = *(const bf16x8*)(wb + (size_t)t * 16 * CHID + s * 32);
            acc[t] = __builtin_amdgcn_mfma_f32_16x16x32_bf16(afr, bfr, acc[t], 0, 0, 0);
        }
    }

    float dv0 = dinv[rowBase + lg * 4 + 0];
    float dv1 = dinv[rowBase + lg * 4 + 1];
    float dv2 = dinv[rowBase + lg * 4 + 2];
    float dv3 = dinv[rowBase + lg * 4 + 3];
#pragma unroll
    for (int t = 0; t < 8; ++t) {
        g2[(size_t)(rowBase + lg * 4 + 0) * COUT + t * 16 + lm] = f2bf(dv0 * acc[t][0]);
        g2[(size_t)(rowBase + lg * 4 + 1) * COUT + t * 16 + lm] = f2bf(dv1 * acc[t][1]);
        g2[(size_t)(rowBase + lg * 4 + 2) * COUT + t * 16 + lm] = f2bf(dv2 * acc[t][2]);
        g2[(size_t)(rowBase + lg * 4 + 3) * COUT + t * 16 + lm] = f2bf(dv3 * acc[t][3]);
    }
}

// ---------------------------------------------------------------------------
// AGG2: out[i] = dinv[i]*(sum g2[src] + g2[i]) + b2
// same half-wave gather structure as aggx (256B bf16 rows, f32 out).
// ---------------------------------------------------------------------------
__global__ __launch_bounds__(256) void agg2_kernel(const unsigned short* __restrict__ g2,
                                                   const int* __restrict__ offs,
                                                   const int* __restrict__ csr,
                                                   const float* __restrict__ dinv,
                                                   const float* __restrict__ b2,
                                                   float* __restrict__ out) {
    int tid = threadIdx.x, wave = tid >> 6, lane = tid & 63;
    int half = lane >> 5, sl = lane & 31;
    int c0 = sl * 4;  // 4 channels/lane; 32 lanes cover 128 channels

    for (int g = blockIdx.x; g < N_NODES / 4; g += gridDim.x) {
        int node = g * 4 + wave;
        int s0 = offs[node];
        int n = offs[node + 1] - s0;

        float4 acc = make_float4(0.f, 0.f, 0.f, 0.f);
        if (half == 0) {  // self loop counted once
            ushort4 sv = *(const ushort4*)(&g2[(size_t)node * COUT + c0]);
            acc.x = bf2f(sv.x); acc.y = bf2f(sv.y);
            acc.z = bf2f(sv.z); acc.w = bf2f(sv.w);
        }

        int nh = (n - half + 1) >> 1;
        int base = s0 + half;
        int nb = nh >> 3;
        int k = 0;
        int i0 = 0, i1 = 0, i2 = 0, i3 = 0, i4 = 0, i5 = 0, i6 = 0, i7 = 0;
        if (nb > 0) {
            i0 = csr[base + 0];  i1 = csr[base + 2];  i2 = csr[base + 4];  i3 = csr[base + 6];
            i4 = csr[base + 8];  i5 = csr[base + 10]; i6 = csr[base + 12]; i7 = csr[base + 14];
        }
        for (int t = 0; t < nb; ++t) {
            ushort4 v0 = *(const ushort4*)(&g2[(size_t)i0 * COUT + c0]);
            ushort4 v1 = *(const ushort4*)(&g2[(size_t)i1 * COUT + c0]);
            ushort4 v2 = *(const ushort4*)(&g2[(size_t)i2 * COUT + c0]);
            ushort4 v3 = *(const ushort4*)(&g2[(size_t)i3 * COUT + c0]);
            ushort4 v4 = *(const ushort4*)(&g2[(size_t)i4 * COUT + c0]);
            ushort4 v5 = *(const ushort4*)(&g2[(size_t)i5 * COUT + c0]);
            ushort4 v6 = *(const ushort4*)(&g2[(size_t)i6 * COUT + c0]);
            ushort4 v7 = *(const ushort4*)(&g2[(size_t)i7 * COUT + c0]);
            int nk = k + 8;
            int j0 = 0, j1 = 0, j2 = 0, j3 = 0, j4 = 0, j5 = 0, j6 = 0, j7 = 0;
            if (t + 1 < nb) {
                const int* cp = csr + base + 2 * nk;
                j0 = cp[0];  j1 = cp[2];  j2 = cp[4];  j3 = cp[6];
                j4 = cp[8];  j5 = cp[10]; j6 = cp[12]; j7 = cp[14];
            }
            acc.x += ((bf2f(v0.x) + bf2f(v1.x)) + (bf2f(v2.x) + bf2f(v3.x))) +
                     ((bf2f(v4.x) + bf2f(v5.x)) + (bf2f(v6.x) + bf2f(v7.x)));
            acc.y += ((bf2f(v0.y) + bf2f(v1.y)) + (bf2f(v2.y) + bf2f(v3.y))) +
                     ((bf2f(v4.y) + bf2f(v5.y)) + (bf2f(v6.y) + bf2f(v7.y)));
            acc.z += ((bf2f(v0.z) + bf2f(v1.z)) + (bf2f(v2.z) + bf2f(v3.z))) +
                     ((bf2f(v4.z) + bf2f(v5.z)) + (bf2f(v6.z) + bf2f(v7.z)));
            acc.w += ((bf2f(v0.w) + bf2f(v1.w)) + (bf2f(v2.w) + bf2f(v3.w))) +
                     ((bf2f(v4.w) + bf2f(v5.w)) + (bf2f(v6.w) + bf2f(v7.w)));
            k = nk;
            i0 = j0; i1 = j1; i2 = j2; i3 = j3; i4 = j4; i5 = j5; i6 = j6; i7 = j7;
        }
        for (; k + 4 <= nh; k += 4) {
            const int* cp = csr + base + 2 * k;
            int k0 = cp[0], k1 = cp[2], k2 = cp[4], k3 = cp[6];
            ushort4 v0 = *(const ushort4*)(&g2[(size_t)k0 * COUT + c0]);
            ushort4 v1 = *(const ushort4*)(&g2[(size_t)k1 * COUT + c0]);
            ushort4 v2 = *(const ushort4*)(&g2[(size_t)k2 * COUT + c0]);
            ushort4 v3 = *(const ushort4*)(&g2[(size_t)k3 * COUT + c0]);
            acc.x += (bf2f(v0.x) + bf2f(v1.x)) + (bf2f(v2.x) + bf2f(v3.x));
            acc.y += (bf2f(v0.y) + bf2f(v1.y)) + (bf2f(v2.y) + bf2f(v3.y));
            acc.z += (bf2f(v0.z) + bf2f(v1.z)) + (bf2f(v2.z) + bf2f(v3.z));
            acc.w += (bf2f(v0.w) + bf2f(v1.w)) + (bf2f(v2.w) + bf2f(v3.w));
        }
        for (; k < nh; ++k) {
            int s = csr[base + 2 * k];
            ushort4 v = *(const ushort4*)(&g2[(size_t)s * COUT + c0]);
            acc.x += bf2f(v.x); acc.y += bf2f(v.y);
            acc.z += bf2f(v.z); acc.w += bf2f(v.w);
        }
        acc.x += __shfl_xor(acc.x, 32);
        acc.y += __shfl_xor(acc.y, 32);
        acc.z += __shfl_xor(acc.z, 32);
        acc.w += __shfl_xor(acc.w, 32);
        if (half == 0) {
            float dv = dinv[node];
            float4 b4 = *(const float4*)(&b2[c0]);
            float4 o;
            o.x = acc.x * dv + b4.x;
            o.y = acc.y * dv + b4.y;
            o.z = acc.z * dv + b4.z;
            o.w = acc.w * dv + b4.w;
            *(float4*)(&out[(size_t)node * COUT + c0]) = o;
        }
    }
}

// ---------------------------------------------------------------------------
extern "C" void kernel_launch(void* const* d_in, const int* in_sizes, int n_in,
                              void* d_out, int out_size, void* d_ws, size_t ws_size,
                              hipStream_t stream) {
    const float* x     = (const float*)d_in[0];
    const int*   ei    = (const int*)d_in[1];
    const float* W1    = (const float*)d_in[2];
    const float* b1    = (const float*)d_in[3];
    const float* gamma = (const float*)d_in[4];
    const float* beta  = (const float*)d_in[5];
    const float* W2    = (const float*)d_in[6];
    const float* b2    = (const float*)d_in[7];
    float* out = (float*)d_out;

    const int* srcv = ei;            // edge_index[0]
    const int* dstv = ei + E_EDGES;  // edge_index[1]

    // workspace layout (g2 aliases xq: xq dead after aggx)
    char* ws = (char*)d_ws;
    size_t off = 0;
    auto alloc = [&](size_t bytes) -> void* {
        void* p = ws + off;
        off += (bytes + 255) & ~(size_t)255;
        return p;
    };
    int*   deg    = (int*)alloc((size_t)N_NODES * 4);
    int*   offs   = (int*)alloc((size_t)(N_NODES + 1) * 4);
    int*   rank   = (int*)alloc((size_t)E_EDGES * 4);
    float* dinv   = (float*)alloc((size_t)N_NODES * 4);
    int*   csr    = (int*)alloc((size_t)E_EDGES * 4);
    unsigned short* xq  = (unsigned short*)alloc((size_t)N_NODES * CIN * 2);  // 8 MB, also g2
    unsigned short* uq  = (unsigned short*)alloc((size_t)N_NODES * CIN * 2);  // 8 MB
    float* h1     = (float*)alloc((size_t)N_NODES * CHID * 4);                // 32 MB
    unsigned short* w1t = (unsigned short*)alloc((size_t)CHID * CIN * 2);     // 64 KB
    unsigned short* w2t = (unsigned short*)alloc((size_t)COUT * CHID * 2);    // 64 KB
    float* stats  = (float*)alloc(2 * CHID * 4);
    float* ab     = (float*)alloc(2 * CHID * 4);
    unsigned short* g2 = xq;

    hipMemsetAsync(deg, 0, (size_t)N_NODES * 4, stream);
    hipMemsetAsync(stats, 0, 2 * CHID * 4, stream);

    deg_kernel<<<E_EDGES / 2 / 256, 256, 0, stream>>>(dstv, deg, rank);
    scan_kernel<<<1, 1024, 0, stream>>>(deg, offs, dinv);
    fill_kernel<<<E_EDGES / 4 / 256, 256, 0, stream>>>(srcv, dstv, rank, offs, csr);

    quantx_kernel<<<N_NODES * CIN / 4 / 256, 256, 0, stream>>>(x, dinv, xq);
    quantw_kernel<<<(CHID * CIN + COUT * CHID) / 256, 256, 0, stream>>>(W1, W2, w1t, w2t);
    aggx_kernel<<<2048, 256, 0, stream>>>(xq, offs, csr, dinv, uq);
    gemm1_kernel<<<N_NODES / 64, 256, 0, stream>>>(uq, w1t, b1, h1, stats);
    bnprep_kernel<<<1, 256, 0, stream>>>(stats, gamma, beta, ab);
    gemm2_kernel<<<N_NODES / 64, 256, 0, stream>>>(h1, ab, w2t, dinv, g2);
    agg2_kernel<<<2048, 256, 0, stream>>>(g2, offs, csr, dinv, b2, out);
}